// Round 3
// baseline (87.391 us; speedup 1.0000x reference)
//
#include <hip/hip_runtime.h>

// RippleLinear: out[b,o] = sum_i amp[i,o] * sin(x[b,i]*freq[i,o] + ph[i,o]) + bias0[o]
//   x:      (2048, 256) f32   (16*128 rows)
//   weight: (256, 256, 2) f32  -> amp = w[i][o][0], freq = w[i][o][1]
//   bias:   (257, 256) f32     -> bias0 = bias[0][:], ph[i][o] = bias[1+i][o]
//   out:    (2048, 256) f32
//
// R7: CLEAN all-poly test (k=16). R6 (k=8 poly + unroll 2) regressed +9.2us
// but was confounded (two changes). Two candidate models give OPPOSITE
// optima:
//   - v_sin at 1/4 rate blocking VALU: cost/iter = 244+4k -> k=0 best
//     (but predicts kernel ~11us; prev session measured ~26us)
//   - v_sin at 1/16 rate blocking VALU: cost/iter = 628-20k -> k=16 best
//     (predicts R5 kernel 25.4us == measured ~26us)
// R7 is the k=16 endpoint with EVERYTHING else identical to the known-75.8
// R5 config: unroll 4, same staging, same reduction, same launch bounds.
// deg-9 odd Taylor sin (8 VALU/sin incl. arg+acc fma), radians -> no
// INV2PI prescale anywhere, x staged RAW. |t| <= ~1.8 -> err ~1.4e-6/sin.
// Prediction: 1/16-rate model -> dur ~62-66us; 1/4-rate model -> ~77-79us.
// Structure unchanged: grid 512 = 256 row-blocks x 2 o-halves, block (64,8),
// thread owns an o-pair, ISPLIT=8 + 3-step LDS tree reduction.

constexpr int IN_F   = 256;
constexpr int OUT_F  = 256;
constexpr int BROWS  = 2048;
constexpr int BTILE  = 8;                 // batch rows per block
constexpr int ISPLIT = 8;                 // i-groups per block (one wave each)
constexpr int ICHUNK = IN_F / ISPLIT;     // 32 i per group
constexpr int OPAIRS = 64;                // o-pairs per block (= 128 o columns)

// deg-9 odd Taylor: sin(t) = t*(1 + t2*(c3 + t2*(c5 + t2*(c7 + t2*c9))))
// |t| <= 1.8 -> err <= t^11/11! ~ 1.4e-6. All full-rate FMA-pipe: 6 VALU.
__device__ __forceinline__ float sin_poly(float t) {
    const float t2 = t * t;
    float q = fmaf(t2, 2.75573192e-6f, -1.98412698e-4f);   // c9, c7
    q = fmaf(q, t2,  8.33333333e-3f);                      // c5
    q = fmaf(q, t2, -0.16666667f);                         // c3
    q = fmaf(q, t2,  1.0f);
    return t * q;
}

__global__ __launch_bounds__(OPAIRS * ISPLIT, 4) void ripple_kernel(
    const float* __restrict__ x,       // (BROWS, IN_F)
    const float* __restrict__ weight,  // (IN_F, OUT_F, 2)
    const float* __restrict__ bias,    // (IN_F+1, OUT_F)
    float* __restrict__ out)           // (BROWS, OUT_F)
{
    const int tx = threadIdx.x;           // 0..63: o-pair lane
    const int g  = threadIdx.y;           // 0..7: i-group (one wave)
    const int ob = blockIdx.x & 1;        // which o-half
    const int bb = blockIdx.x >> 1;       // row-block
    const int b0 = bb * BTILE;
    const int oc = ob * OPAIRS + tx;      // global o-pair index 0..127

    __shared__ __align__(16) float xs_t[BTILE * IN_F];  // 8 KB, xs_t[i*8+r] = raw x (radians)
    __shared__ float2 red[4][BTILE][OPAIRS];            // 16 KB reduction buffer

    // --- stage x-tile transposed (RAW): 512 threads x float4 ---
    {
        const int t  = g * OPAIRS + tx;   // 0..511
        const int r  = t >> 6;            // row 0..7
        const int c4 = t & 63;            // float4 column
        const float4 v = ((const float4*)x)[(b0 + r) * (IN_F / 4) + c4];
        xs_t[(4 * c4 + 0) * BTILE + r] = v.x;
        xs_t[(4 * c4 + 1) * BTILE + r] = v.y;
        xs_t[(4 * c4 + 2) * BTILE + r] = v.z;
        xs_t[(4 * c4 + 3) * BTILE + r] = v.w;
    }
    __syncthreads();

    float acc0[BTILE], acc1[BTILE];
#pragma unroll
    for (int r = 0; r < BTILE; ++r) { acc0[r] = 0.0f; acc1[r] = 0.0f; }

    const float4* __restrict__ wq  = (const float4*)weight;  // (amp0,freq0,amp1,freq1)
    const float2* __restrict__ ph2 = (const float2*)bias;    // phase pairs

    const int i0 = g * ICHUNK;
#pragma unroll 4
    for (int ii = 0; ii < ICHUNK; ++ii) {
        const int i = i0 + ii;
        const float4 w = wq[i * (OUT_F / 2) + oc];           // 16B coalesced
        const float2 p = ph2[(i + 1) * (OUT_F / 2) + oc];    // 8B coalesced
        const float4 xa = *(const float4*)&xs_t[i * BTILE];      // rows 0..3
        const float4 xb = *(const float4*)&xs_t[i * BTILE + 4];  // rows 4..7
        const float xv[BTILE] = {xa.x, xa.y, xa.z, xa.w, xb.x, xb.y, xb.z, xb.w};
#pragma unroll
        for (int r = 0; r < BTILE; ++r) {
            acc0[r] = fmaf(w.x, sin_poly(fmaf(xv[r], w.y, p.x)), acc0[r]);
            acc1[r] = fmaf(w.z, sin_poly(fmaf(xv[r], w.w, p.y)), acc1[r]);
        }
    }

    // --- 3-step cross-wave tree reduction over the 8 i-groups ---
    if (g >= 4) {
#pragma unroll
        for (int r = 0; r < BTILE; ++r) red[g - 4][r][tx] = make_float2(acc0[r], acc1[r]);
    }
    __syncthreads();
    if (g < 4) {
#pragma unroll
        for (int r = 0; r < BTILE; ++r) { float2 t = red[g][r][tx]; acc0[r] += t.x; acc1[r] += t.y; }
    }
    __syncthreads();
    if (g == 2 || g == 3) {
#pragma unroll
        for (int r = 0; r < BTILE; ++r) red[g - 2][r][tx] = make_float2(acc0[r], acc1[r]);
    }
    __syncthreads();
    if (g < 2) {
#pragma unroll
        for (int r = 0; r < BTILE; ++r) { float2 t = red[g][r][tx]; acc0[r] += t.x; acc1[r] += t.y; }
    }
    __syncthreads();
    if (g == 1) {
#pragma unroll
        for (int r = 0; r < BTILE; ++r) red[0][r][tx] = make_float2(acc0[r], acc1[r]);
    }
    __syncthreads();
    if (g == 0) {
        const float2 bo = ph2[oc];   // bias row 0, this o-pair
#pragma unroll
        for (int r = 0; r < BTILE; ++r) {
            float2 t = red[0][r][tx];
            float2 v = make_float2(acc0[r] + t.x + bo.x, acc1[r] + t.y + bo.y);
            ((float2*)out)[(b0 + r) * (OUT_F / 2) + oc] = v;
        }
    }
}

extern "C" void kernel_launch(void* const* d_in, const int* in_sizes, int n_in,
                              void* d_out, int out_size, void* d_ws, size_t ws_size,
                              hipStream_t stream) {
    const float* x      = (const float*)d_in[0];
    const float* weight = (const float*)d_in[1];
    const float* bias   = (const float*)d_in[2];
    float* out          = (float*)d_out;

    dim3 grid((BROWS / BTILE) * 2);     // 512 blocks: 256 row-blocks x 2 o-halves
    dim3 block(OPAIRS, ISPLIT);         // 512 threads = 8 waves
    ripple_kernel<<<grid, block, 0, stream>>>(x, weight, bias, out);
}

// Round 4
// 77.383 us; speedup vs baseline: 1.1293x; 1.1293x over previous
//
#include <hip/hip_runtime.h>

// RippleLinear: out[b,o] = sum_i amp[i,o] * sin(x[b,i]*freq[i,o] + ph[i,o]) + bias0[o]
//   x:      (2048, 256) f32   (16*128 rows)
//   weight: (256, 256, 2) f32  -> amp = w[i][o][0], freq = w[i][o][1]
//   bias:   (257, 256) f32     -> bias0 = bias[0][:], ph[i][o] = bias[1+i][o]
//   out:    (2048, 256) f32
//
// R8. History: R5 (v_sin) 75.8 | R6 (half poly) 85.0 | R7 (all poly) 87.4.
// Poly REGRESSED at both endpoints -> trans-pipe-bound theory dead; v_sin is
// ~1/4-rate, cheaper than 6 FMAs. Yet measured kernel (~26us) sits 2-3x above
// the VALU-issue floor (~7-12us), and R7's slowdown tracks the DEPENDENCY-
// CHAIN ratio, not the issue ratio. Revised theory: LATENCY-BOUND at low
// occupancy -- 512 blocks = 2 blocks/CU = 4 waves/SIMD only.
// Fix: BTILE 8->4 => grid 1024 = 4 blocks/CU target; LDS 24->12 KB;
// accs halve; __launch_bounds__(512,8) caps VGPR at 64 => 8 waves/SIMD.
// Arithmetic reverted to R5's proven v_sin form (x prescaled by 1/2pi at
// staging; phase scaled once per iter; 3 VALU + 1 v_sin per sin).
// x-tile read is now ONE broadcast ds_read_b128 per iter (conflict-free).
// Prediction: dur 75.8 -> ~62-66 if latency-bound; neutral => issue-bound
// floor reached; >85 => spill (relax cap next).

constexpr int IN_F   = 256;
constexpr int OUT_F  = 256;
constexpr int BROWS  = 2048;
constexpr int BTILE  = 4;                 // batch rows per block (was 8)
constexpr int ISPLIT = 8;                 // i-groups per block (one wave each)
constexpr int ICHUNK = IN_F / ISPLIT;     // 32 i per group
constexpr int OPAIRS = 64;                // o-pairs per block (= 128 o columns)

#define INV2PI 0.15915494309189535f

__global__ __launch_bounds__(OPAIRS * ISPLIT, 8) void ripple_kernel(
    const float* __restrict__ x,       // (BROWS, IN_F)
    const float* __restrict__ weight,  // (IN_F, OUT_F, 2)
    const float* __restrict__ bias,    // (IN_F+1, OUT_F)
    float* __restrict__ out)           // (BROWS, OUT_F)
{
    const int tx = threadIdx.x;           // 0..63: o-pair lane
    const int g  = threadIdx.y;           // 0..7: i-group (one wave)
    const int ob = blockIdx.x & 1;        // which o-half
    const int bb = blockIdx.x >> 1;       // row-block
    const int b0 = bb * BTILE;
    const int oc = ob * OPAIRS + tx;      // global o-pair index 0..127

    __shared__ __align__(16) float xs_t[BTILE * IN_F];  // 4 KB, xs_t[i*4+r] = x/(2pi)
    __shared__ float2 red[4][BTILE][OPAIRS];            // 8 KB reduction buffer

    // --- stage x-tile transposed + prescaled: 256 of 512 threads x float4 ---
    {
        const int t = g * OPAIRS + tx;    // 0..511
        if (t < BTILE * (IN_F / 4)) {     // 256 loaders
            const int r  = t >> 6;        // row 0..3
            const int c4 = t & 63;        // float4 column
            const float4 v = ((const float4*)x)[(b0 + r) * (IN_F / 4) + c4];
            xs_t[(4 * c4 + 0) * BTILE + r] = v.x * INV2PI;
            xs_t[(4 * c4 + 1) * BTILE + r] = v.y * INV2PI;
            xs_t[(4 * c4 + 2) * BTILE + r] = v.z * INV2PI;
            xs_t[(4 * c4 + 3) * BTILE + r] = v.w * INV2PI;
        }
    }
    __syncthreads();

    float acc0[BTILE], acc1[BTILE];
#pragma unroll
    for (int r = 0; r < BTILE; ++r) { acc0[r] = 0.0f; acc1[r] = 0.0f; }

    const float4* __restrict__ wq  = (const float4*)weight;  // (amp0,freq0,amp1,freq1)
    const float2* __restrict__ ph2 = (const float2*)bias;    // phase pairs

    const int i0 = g * ICHUNK;
#pragma unroll 4
    for (int ii = 0; ii < ICHUNK; ++ii) {
        const int i = i0 + ii;
        const float4 w = wq[i * (OUT_F / 2) + oc];           // 16B coalesced
        const float2 p = ph2[(i + 1) * (OUT_F / 2) + oc];    // 8B coalesced
        const float px = p.x * INV2PI;
        const float py = p.y * INV2PI;
        const float4 xa = *(const float4*)&xs_t[i * BTILE];  // rows 0..3 (broadcast)
        const float xv[BTILE] = {xa.x, xa.y, xa.z, xa.w};
#pragma unroll
        for (int r = 0; r < BTILE; ++r) {
            acc0[r] += w.x * __builtin_amdgcn_sinf(fmaf(xv[r], w.y, px));
            acc1[r] += w.z * __builtin_amdgcn_sinf(fmaf(xv[r], w.w, py));
        }
    }

    // --- 3-step cross-wave tree reduction over the 8 i-groups ---
    if (g >= 4) {
#pragma unroll
        for (int r = 0; r < BTILE; ++r) red[g - 4][r][tx] = make_float2(acc0[r], acc1[r]);
    }
    __syncthreads();
    if (g < 4) {
#pragma unroll
        for (int r = 0; r < BTILE; ++r) { float2 t = red[g][r][tx]; acc0[r] += t.x; acc1[r] += t.y; }
    }
    __syncthreads();
    if (g == 2 || g == 3) {
#pragma unroll
        for (int r = 0; r < BTILE; ++r) red[g - 2][r][tx] = make_float2(acc0[r], acc1[r]);
    }
    __syncthreads();
    if (g < 2) {
#pragma unroll
        for (int r = 0; r < BTILE; ++r) { float2 t = red[g][r][tx]; acc0[r] += t.x; acc1[r] += t.y; }
    }
    __syncthreads();
    if (g == 1) {
#pragma unroll
        for (int r = 0; r < BTILE; ++r) red[0][r][tx] = make_float2(acc0[r], acc1[r]);
    }
    __syncthreads();
    if (g == 0) {
        const float2 bo = ph2[oc];   // bias row 0, this o-pair (unscaled)
#pragma unroll
        for (int r = 0; r < BTILE; ++r) {
            float2 t = red[0][r][tx];
            float2 v = make_float2(acc0[r] + t.x + bo.x, acc1[r] + t.y + bo.y);
            ((float2*)out)[(b0 + r) * (OUT_F / 2) + oc] = v;
        }
    }
}

extern "C" void kernel_launch(void* const* d_in, const int* in_sizes, int n_in,
                              void* d_out, int out_size, void* d_ws, size_t ws_size,
                              hipStream_t stream) {
    const float* x      = (const float*)d_in[0];
    const float* weight = (const float*)d_in[1];
    const float* bias   = (const float*)d_in[2];
    float* out          = (float*)d_out;

    dim3 grid((BROWS / BTILE) * 2);     // 1024 blocks: 512 row-blocks x 2 o-halves
    dim3 block(OPAIRS, ISPLIT);         // 512 threads = 8 waves
    ripple_kernel<<<grid, block, 0, stream>>>(x, weight, bias, out);
}